// Round 12
// baseline (103.577 us; speedup 1.0000x reference)
//
#include <hip/hip_runtime.h>
#include <math.h>

// ---- problem constants ----
#define SEQ 64
#define NSAMP 16384
#define NHARM 32
#define NWS 512
#define NSTEP 256
#define BE 128            // B*E = 8*16
#define NFRAMES 8192      // BE * SEQ

typedef _Float16 half8 __attribute__((ext_vector_type(8)));
typedef float f32x4 __attribute__((ext_vector_type(4)));

__device__ __forceinline__ float sin_rev(float x) {  // sin(2*pi*x)
  float r; asm("v_sin_f32 %0, %1" : "=v"(r) : "v"(x)); return r;
}
__device__ __forceinline__ float cos_rev(float x) {  // cos(2*pi*x)
  float r; asm("v_cos_f32 %0, %1" : "=v"(r) : "v"(x)); return r;
}
__device__ __forceinline__ float clip01(float v) { return fminf(fmaxf(v, 0.0f), 1.0f); }

__device__ __forceinline__ float f0_to_norm(float f0v, float bl) {
  const float NYQ = 11025.0f;
  const float MIN_F0 = 20.0f / 11025.0f;
  const float F0_DIFF = 780.0f / 11025.0f;
  float v = fminf(fmaxf(f0v, -0.5f), 0.5f);
  float erb = (0.108f * (bl * NYQ) + 24.7f) / NYQ;
  float fv = clip01(bl + v * erb);
  return MIN_F0 + fv * F0_DIFF;
}

// ---------------------------------------------------------------------------
// Single fused kernel, 1024 blocks x 256 threads, 4 blocks/CU co-resident.
// Block p: PRODUCE AB stripe ms (32 frames x 64 kappa, fwd GEMM + filter),
// flag[ms]++, then CONSUME tile (be=ms>>1, chalf=ms&1, n0=bn0): inverse GEMM
// + OLA + oscillator bank + mix -> out. Consumer needs only its own stripe
// (3 sibling blocks, same XCD via swizzle) and stripe ms-1 when chalf==1.
// NOT an R9-style global barrier: 256 flag lines, <=8 short-lived waiters.
// ---------------------------------------------------------------------------
__global__ __launch_bounds__(256, 4) void fused_k(
    const float* __restrict__ Af,        // noise_frames [8192][512] f32
    const float* __restrict__ f0,
    const float* __restrict__ nstd,
    const float* __restrict__ f0b,
    const float* __restrict__ oenv_g,
    const float* __restrict__ oscenv_g,
    const float* __restrict__ henv_g,
    _Float16* __restrict__ AB,           // [8192][256]
    unsigned int* __restrict__ flags,    // [256], pre-zeroed
    float* __restrict__ out) {
  __shared__ __align__(16) unsigned char smem[30464];
  const int p = blockIdx.x;
  const int tid = threadIdx.x;
  const int x = p & 7, j = p >> 3;          // XCD swizzle decode
  const int mstripe = ((j >> 2) << 3) + x;  // [0,256): 4 siblings share p%8
  const int bn0 = (j & 3) * 64;
  const int m0 = mstripe * 32;
  const int wave = tid >> 6, lane = tid & 63;
  const int r = lane & 15, q = lane >> 4;
  const int wr = (wave & 1) * 16;
  const int wc = (wave >> 1) * 32;

  // ================= PRODUCE: fwd GEMM + Gaussian filter -> AB ============
  {
    _Float16* Ash = (_Float16*)smem;            // [2][32*64] = 8 KB
    _Float16* Bsh = (_Float16*)(smem + 8192);   // [2][64*64] = 16 KB
    float* whann = (float*)(smem + 24576);      // [512] = 2 KB

    const int Kt = 512;
    const int nT = 8;
    const int srowA = tid >> 3;
    const int srowB0 = tid >> 3, srowB1 = (256 + tid) >> 3;
    const int skg = tid & 7;

    half8 ra, rb[2];
    f32x4 acc[2] = {};

    whann[tid] = 0.5f - 0.5f * cos_rev((float)tid * (1.0f / 512.0f));
    whann[tid + 256] = 0.5f - 0.5f * cos_rev((float)(tid + 256) * (1.0f / 512.0f));
    __syncthreads();

    const int kB0 = (bn0 + srowB0) & 127;
    const int kB1 = (bn0 + srowB1) & 127;
    const bool sB0 = (bn0 + srowB0) >= 128;
    const bool sB1 = (bn0 + srowB1) >= 128;

    auto load_a = [&](int kk) {
      const float* s0 = Af + (size_t)(m0 + srowA) * Kt + kk + skg * 8;
      float4 a0 = ((const float4*)s0)[0], a1 = ((const float4*)s0)[1];
      float4 w0 = *(const float4*)(&whann[kk + skg * 8]);
      float4 w1 = *(const float4*)(&whann[kk + skg * 8 + 4]);
      ra[0] = (_Float16)(a0.x * w0.x); ra[1] = (_Float16)(a0.y * w0.y);
      ra[2] = (_Float16)(a0.z * w0.z); ra[3] = (_Float16)(a0.w * w0.w);
      ra[4] = (_Float16)(a1.x * w1.x); ra[5] = (_Float16)(a1.y * w1.y);
      ra[6] = (_Float16)(a1.z * w1.z); ra[7] = (_Float16)(a1.w * w1.w);
    };
    auto gen_b = [&](int kk) {  // W1 twiddles via trig (bit-identical)
      const int nbase = kk + skg * 8;
#pragma unroll
      for (int jj = 0; jj < 8; ++jj) {
        const int n = nbase + jj;
        float ph0 = (float)((kB0 * n) & 511) * (1.0f / 512.0f);
        float ph1 = (float)((kB1 * n) & 511) * (1.0f / 512.0f);
        rb[0][jj] = (_Float16)(sB0 ? sin_rev(ph0) : cos_rev(ph0));
        rb[1][jj] = (_Float16)(sB1 ? sin_rev(ph1) : cos_rev(ph1));
      }
    };
    auto store_lds = [&](int b) {
      *(half8*)(&Ash[b * 2048 + srowA * 64 + ((skg ^ (srowA & 7)) << 3)]) = ra;
      *(half8*)(&Bsh[b * 4096 + srowB0 * 64 + ((skg ^ (srowB0 & 7)) << 3)]) = rb[0];
      *(half8*)(&Bsh[b * 4096 + srowB1 * 64 + ((skg ^ (srowB1 & 7)) << 3)]) = rb[1];
    };

    load_a(0);
    gen_b(0);
    store_lds(0);

    for (int t = 0;;) {
      if (t + 1 < nT) { load_a((t + 1) << 6); gen_b((t + 1) << 6); }
      __syncthreads();
      const int b = t & 1;
#pragma unroll
      for (int ks = 0; ks < 2; ++ks) {
        const int kg = ks * 4 + q;
        const int ar = wr + r;
        half8 af = *(const half8*)(&Ash[b * 2048 + ar * 64 + ((kg ^ (ar & 7)) << 3)]);
#pragma unroll
        for (int ni = 0; ni < 2; ++ni) {
          const int br = wc + ni * 16 + r;
          half8 bf = *(const half8*)(&Bsh[b * 4096 + br * 64 + ((kg ^ (br & 7)) << 3)]);
          acc[ni] = __builtin_amdgcn_mfma_f32_16x16x32_f16(af, bf, acc[ni], 0, 0, 0);
        }
      }
      if (t + 1 >= nT) break;
      __syncthreads();
      store_lds((t + 1) & 1);
      ++t;
    }

    const float F0_DIFF = 780.0f / 11025.0f;
#pragma unroll
    for (int reg = 0; reg < 4; ++reg) {
      const int row = m0 + wr + q * 4 + reg;   // frame
      const float mu = f0_to_norm(f0[row], f0b[row >> 6]);
      const float sd = fminf(fmaxf(nstd[row], 1e-12f), 1.0f) * F0_DIFF;
      const float inv_sd = 1.0f / sd;
      const float a = inv_sd * (1.0f / 256.0f);
      const float bmu = mu * inv_sd;
#pragma unroll
      for (int ni = 0; ni < 2; ++ni) {
        const int col = bn0 + wc + ni * 16 + r;  // kappa
        const int k = col & 127;
        float z = fmaf((float)k, a, -bmu);
        float cf = (k == 0) ? (1.0f / 512.0f) : (2.0f / 512.0f);
        float s = cf * exp2f(z * z * -0.72134752044f);  // exp(-z^2/2)
        AB[(size_t)row * 256 + col] = (_Float16)(acc[ni][reg] * s);
      }
    }
  }

  // publish: all AB writes of this block drained (syncthreads), then flag
  __syncthreads();
  if (tid == 0) {
    __threadfence();
    __hip_atomic_fetch_add(&flags[mstripe], 1u, __ATOMIC_ACQ_REL,
                           __HIP_MEMORY_SCOPE_AGENT);
  }

  // ================= CONSUME: inv GEMM + OLA + oscillator + mix ===========
  const int be = mstripe >> 1;
  const int chalf = mstripe & 1;
  const int n0c = bn0;                 // sample-within-chunk base
  // A-tile rows: AB[m0-1 .. m0+31]  (m0 == be*64 + chalf*32)

  _Float16* A2sh = (_Float16*)smem;            // [33*64]
  _Float16* B1sh = (_Float16*)(smem + 4224);   // [64*64]
  _Float16* B2sh = (_Float16*)(smem + 12416);  // [64*64]
  float4* qe4 = (float4*)(smem + 20608);       // [8*64]
  float* oenv = (float*)(smem + 28800);
  float* oscE = (float*)(smem + 29056);
  float* Fs = (float*)(smem + 29312);
  float* Ds = (float*)(smem + 29568);
  float* Gs = (float*)(smem + 29824);

  if (tid < SEQ) {
    oenv[tid] = clip01(oenv_g[be * SEQ + tid]);
    oscE[tid] = clip01(oscenv_g[be * SEQ + tid]);
    Fs[tid] = f0_to_norm(f0[be * SEQ + tid], f0b[be]);
  }
  __syncthreads();

  // wave 0: segment phase-prefix scan (f64, 6 shuffle steps), mod 2
  if (tid < SEQ) {
    const int s = tid;
    float fcur = Fs[s];
    float fnxt = (s < 63) ? Fs[s + 1] : Fs[63];
    Ds[s] = fnxt - fcur;                               // D[63] = 0
    double term = 128.0 * ((double)fcur + (double)fnxt);
    double sc = term;
#pragma unroll
    for (int off = 1; off < 64; off <<= 1) {
      double u = __shfl_up(sc, off, 64);
      if (s >= off) sc += u;
    }
    double C = 128.0 * (double)Fs[0] + (sc - term);    // exclusive prefix
    Gs[s] = (float)(C - 2.0 * floor(C * 0.5));
  }

  // stage qe4 (osc_env * harm_env) — AB-independent, before the flag wait
  for (int idx = tid; idx < 8 * SEQ; idx += 256) {
    int hq = idx >> 6, s = idx & 63;
    const float* hb = henv_g + (size_t)be * (NHARM * SEQ) + (4 * hq) * SEQ + s;
    float e = oscE[s];
    qe4[idx] = make_float4(e * clip01(hb[0]), e * clip01(hb[64]),
                           e * clip01(hb[128]), e * clip01(hb[192]));
  }

  // staging state: A from global (after flags), B (W2) via trig (independent)
  half8 raA0, raA1, rbB[4];
  const int rowA0 = tid >> 3, kgA0 = tid & 7;
  const int rowA1 = (256 + tid) >> 3;

  auto gen_w2 = [&](int kk) {  // W2 row n, kappa slice [kk,kk+64): uniform
#pragma unroll
    for (int it = 0; it < 4; ++it) {
      int g = it * 256 + tid;
      int row = (g >> 3) & 63;
      int n = n0c + row + ((g >= 512) ? 256 : 0);
#pragma unroll
      for (int jj = 0; jj < 8; ++jj) {
        int kap = kk + (g & 7) * 8 + jj;
        int k = kap & 127;
        float ph = (float)((k * n) & 511) * (1.0f / 512.0f);
        rbB[it][jj] = (_Float16)((kap >= 128) ? sin_rev(ph) : cos_rev(ph));
      }
    }
  };
  auto load_a2 = [&](int kk) {
    half8 v = {0, 0, 0, 0, 0, 0, 0, 0};
    if (rowA0 > 0 || chalf == 1)
      v = *(const half8*)(AB + (size_t)(m0 - 1 + rowA0) * 256 + kk + kgA0 * 8);
    raA0 = v;
    if (tid < 8)
      raA1 = *(const half8*)(AB + (size_t)(m0 - 1 + rowA1) * 256 + kk + kgA0 * 8);
  };
  auto write_b = [&]() {
#pragma unroll
    for (int it = 0; it < 4; ++it) {
      int g = it * 256 + tid;
      int row = (g >> 3) & 63;
      _Float16* dst = (g >= 512) ? B2sh : B1sh;
      *(half8*)(&dst[row * 64 + (((g & 7) ^ (row & 7)) << 3)]) = rbB[it];
    }
  };
  auto write_a = [&]() {
    *(half8*)(&A2sh[rowA0 * 64 + ((kgA0 ^ (rowA0 & 7)) << 3)]) = raA0;
    if (tid < 8)
      *(half8*)(&A2sh[rowA1 * 64 + ((kgA0 ^ (rowA1 & 7)) << 3)]) = raA1;
  };

  gen_w2(0);
  write_b();

  // wait for sibling producers (and stripe ms-1 for chalf==1)
  if (tid == 0) {
    while (__hip_atomic_load(&flags[mstripe], __ATOMIC_ACQUIRE,
                             __HIP_MEMORY_SCOPE_AGENT) < 4u)
      __builtin_amdgcn_s_sleep(4);
    if (chalf)
      while (__hip_atomic_load(&flags[mstripe - 1], __ATOMIC_ACQUIRE,
                               __HIP_MEMORY_SCOPE_AGENT) < 4u)
        __builtin_amdgcn_s_sleep(4);
  }
  __syncthreads();

  f32x4 acc[2] = {};
  load_a2(0);
  write_a();
  __syncthreads();

  // K-loop: 4 steps of BK=64; T14 prefetch (A loads + W2 trig) before MFMA
  for (int t = 0;;) {
    if (t < 3) { load_a2((t + 1) << 6); gen_w2((t + 1) << 6); }
#pragma unroll
    for (int ks = 0; ks < 2; ++ks) {
      const int kg = ks * 4 + q;
      const int ra1 = 1 + wr + r;
      const int ra2 = wr + r;
      half8 af1 = *(const half8*)(&A2sh[ra1 * 64 + ((kg ^ (ra1 & 7)) << 3)]);
      half8 af2 = *(const half8*)(&A2sh[ra2 * 64 + ((kg ^ (ra2 & 7)) << 3)]);
#pragma unroll
      for (int ni = 0; ni < 2; ++ni) {
        const int rb = wc + ni * 16 + r;
        const int sw = (kg ^ (rb & 7)) << 3;
        half8 bf1 = *(const half8*)(&B1sh[rb * 64 + sw]);
        half8 bf2 = *(const half8*)(&B2sh[rb * 64 + sw]);
        acc[ni] = __builtin_amdgcn_mfma_f32_16x16x32_f16(af1, bf1, acc[ni], 0, 0, 0);
        acc[ni] = __builtin_amdgcn_mfma_f32_16x16x32_f16(af2, bf2, acc[ni], 0, 0, 0);
      }
    }
    if (t == 3) break;
    __syncthreads();
    write_a();
    write_b();
    __syncthreads();
    ++t;
  }

  // epilogue: analytic phase + oscillator bank + mix, in-register
#pragma unroll
  for (int reg = 0; reg < 4; ++reg) {
    const int c = chalf * 32 + wr + q * 4 + reg;     // chunk within be
#pragma unroll
    for (int ni = 0; ni < 2; ++ni) {
      const int n = n0c + wc + ni * 16 + r;
      const int t = c * 256 + n;
      float pos = ((float)t + 0.5f) * (1.0f / 256.0f) - 0.5f;
      pos = fminf(fmaxf(pos, 0.0f), 63.0f);
      int i0 = (int)pos;
      int i1 = min(i0 + 1, 63);
      float w = pos - (float)i0;

      float pph;
      if (t < 128) {
        pph = (float)(t + 1) * Fs[0];
      } else {
        int s = (t - 128) >> 8;
        float u1 = (float)((t - 128) - (s << 8) + 1);
        pph = Gs[s] + fmaf(Ds[s] * (1.0f / 512.0f), u1 * u1, u1 * Fs[s]);
      }
      pph = pph - 2.0f * floorf(pph * 0.5f);         // phase mod 2 (pi units)
      float xv = pph * 0.5f;
      float sb = sin_rev(xv);
      float cb = cos_rev(xv);
      float C = 2.0f * cb;

      float fund = sb * (oscE[i0] * (1.0f - w) + oscE[i1] * w);
      float d0 = 0.0f, d1 = 0.0f;
      float sp = sb;
      float scur = C * sb;
#pragma unroll
      for (int hq = 0; hq < 8; ++hq) {
        float4 qa = qe4[hq * 64 + i0];
        float4 qb = qe4[hq * 64 + i1];
        d0 = fmaf(scur, qa.x, d0); d1 = fmaf(scur, qb.x, d1);
        sp = fmaf(C, scur, -sp);
        d0 = fmaf(sp, qa.y, d0);   d1 = fmaf(sp, qb.y, d1);
        scur = fmaf(C, sp, -scur);
        d0 = fmaf(scur, qa.z, d0); d1 = fmaf(scur, qb.z, d1);
        sp = fmaf(C, scur, -sp);
        d0 = fmaf(sp, qa.w, d0);   d1 = fmaf(sp, qb.w, d1);
        scur = fmaf(C, sp, -scur);
      }
      float osc = fund + d0 * (1.0f - w) + d1 * w;
      float mix = oenv[i0] * (1.0f - w) + oenv[i1] * w;
      out[(size_t)be * NSAMP + t] = fmaf(osc, mix, acc[ni][reg] * (1.0f - mix));
    }
  }
}

// ---------------------------------------------------------------------------
extern "C" void kernel_launch(void* const* d_in, const int* in_sizes, int n_in,
                              void* d_out, int out_size, void* d_ws, size_t ws_size,
                              hipStream_t stream) {
  const float* f0           = (const float*)d_in[0];
  const float* overall_env  = (const float*)d_in[1];
  const float* osc_env      = (const float*)d_in[2];
  // d_in[3] = noise_env: unused by the reference
  const float* harm_env     = (const float*)d_in[4];
  const float* noise_std    = (const float*)d_in[5];
  const float* f0_base      = (const float*)d_in[6];
  const float* noise_frames = (const float*)d_in[7];
  float* out = (float*)d_out;

  // workspace layout
  _Float16* AB = (_Float16*)d_ws;                          // 2,097,152 f16
  unsigned int* flags = (unsigned int*)(AB + (size_t)NFRAMES * 256);  // 256 u32

  // zero the per-stripe flags (deterministic across graph replays)
  hipMemsetAsync(flags, 0, 256 * sizeof(unsigned int), stream);

  fused_k<<<1024, 256, 0, stream>>>(
      noise_frames, f0, noise_std, f0_base, overall_env, osc_env, harm_env,
      AB, flags, out);
}

// Round 13
// 83.280 us; speedup vs baseline: 1.2437x; 1.2437x over previous
//
#include <hip/hip_runtime.h>
#include <math.h>

// ---- problem constants ----
#define SEQ 64
#define NSAMP 16384
#define NHARM 32
#define BE 128            // B*E = 8*16
#define NFRAMES 8192      // BE * SEQ

typedef _Float16 half8 __attribute__((ext_vector_type(8)));
typedef float f32x4 __attribute__((ext_vector_type(4)));

__device__ __forceinline__ float sin_rev(float x) {  // sin(2*pi*x)
  float r; asm("v_sin_f32 %0, %1" : "=v"(r) : "v"(x)); return r;
}
__device__ __forceinline__ float cos_rev(float x) {  // cos(2*pi*x)
  float r; asm("v_cos_f32 %0, %1" : "=v"(r) : "v"(x)); return r;
}
__device__ __forceinline__ float clip01(float v) { return fminf(fmaxf(v, 0.0f), 1.0f); }

__device__ __forceinline__ float f0_to_norm(float f0v, float bl) {
  const float NYQ = 11025.0f;
  const float MIN_F0 = 20.0f / 11025.0f;
  const float F0_DIFF = 780.0f / 11025.0f;
  float v = fminf(fmaxf(f0v, -0.5f), 0.5f);
  float erb = (0.108f * (bl * NYQ) + 24.7f) / NYQ;
  float fv = clip01(bl + v * erb);
  return MIN_F0 + fv * F0_DIFF;
}

// ---------------------------------------------------------------------------
// Monolithic kernel: block = (be, qc) handles 8 output chunks of one (b,e).
// 1) stage 9 windowed chunk-frames (8 output + 1 OLA boundary) -> LDS f16
// 2) fwd DFT GEMM (M=16/9-real, N=256, K=512), W1 B-frags trig-in-regs,
//    Gaussian filter epilogue -> AB_local in LDS (10 rows x 256 kappa)
// 3) inv DFT GEMM + OLA (dual MFMA: af1*W2[n] + af2*W2[n+256])
// 4) analytic-phase oscillator bank + mix epilogue -> out
// Zero inter-block communication; 3 __syncthreads; no workspace.
// ---------------------------------------------------------------------------
__global__ __launch_bounds__(256, 4) void mono_k(
    const float* __restrict__ Af,        // noise_frames [8192][512] f32
    const float* __restrict__ f0,
    const float* __restrict__ nstd,
    const float* __restrict__ f0b,
    const float* __restrict__ oenv_g,
    const float* __restrict__ oscenv_g,
    const float* __restrict__ henv_g,
    float* __restrict__ out) {
  __shared__ __align__(16) _Float16 A_all[10 * 512];   // 10240 B: frames f16
  __shared__ __align__(16) _Float16 ABl[10 * 256];     // 5120 B: filtered spec
  __shared__ __align__(16) float whann[512];           // 2048 B
  __shared__ __align__(16) float4 qe4[8 * SEQ];        // 8192 B
  __shared__ float oenv[SEQ], oscE[SEQ], Fs[SEQ], Ds[SEQ], Gs[SEQ];

  const int p = blockIdx.x;                 // [0,1024)
  const int be = p >> 3, qc = p & 7;
  const int c0 = be * 64 + qc * 8;          // first output chunk (global)
  const int tid = threadIdx.x;
  const int wave = tid >> 6, lane = tid & 63;
  const int r = lane & 15, q = lane >> 4;
  const int wc = wave * 64;                 // wave's kappa/sample column base

  // ---------- phase A: independent small staging ----------
  whann[tid] = 0.5f - 0.5f * cos_rev((float)tid * (1.0f / 512.0f));
  whann[tid + 256] = 0.5f - 0.5f * cos_rev((float)(tid + 256) * (1.0f / 512.0f));
  if (tid < SEQ) {
    oenv[tid] = clip01(oenv_g[be * SEQ + tid]);
    oscE[tid] = clip01(oscenv_g[be * SEQ + tid]);
    Fs[tid] = f0_to_norm(f0[be * SEQ + tid], f0b[be]);
  }
  for (int idx = tid; idx < 8 * SEQ; idx += 256) {
    int hq = idx >> 6, s = idx & 63;
    const float* hb = henv_g + (size_t)be * (NHARM * SEQ) + (4 * hq) * SEQ + s;
    float e = clip01(oscenv_g[be * SEQ + s]);   // from global: no dep on oscE
    qe4[idx] = make_float4(e * clip01(hb[0]), e * clip01(hb[64]),
                           e * clip01(hb[128]), e * clip01(hb[192]));
  }
  __syncthreads();

  // ---------- phase B: phase-prefix scan + windowed frame staging ----------
  if (tid < SEQ) {  // wave 0: f64 shuffle scan, mod 2 (identical to R11)
    const int s = tid;
    float fcur = Fs[s];
    float fnxt = (s < 63) ? Fs[s + 1] : Fs[63];
    Ds[s] = fnxt - fcur;
    double term = 128.0 * ((double)fcur + (double)fnxt);
    double sc = term;
#pragma unroll
    for (int off = 1; off < 64; off <<= 1) {
      double u = __shfl_up(sc, off, 64);
      if (s >= off) sc += u;
    }
    double C = 128.0 * (double)Fs[0] + (sc - term);
    Gs[s] = (float)(C - 2.0 * floor(C * 0.5));
  }
  // A_all rows 0..8 = frames c0-1 .. c0+7 (clamped), row 9 = zeros
  for (int g = tid; g < 640; g += 256) {
    int row = g >> 6, kg = g & 63;
    half8 v = {0, 0, 0, 0, 0, 0, 0, 0};
    if (row < 9) {
      int fi = max(c0 - 1 + row, 0);          // c0+7 <= 8191 always
      const float* s0 = Af + (size_t)fi * 512 + kg * 8;
      float4 a0 = ((const float4*)s0)[0], a1 = ((const float4*)s0)[1];
      float4 w0 = *(const float4*)(&whann[kg * 8]);
      float4 w1 = *(const float4*)(&whann[kg * 8 + 4]);
      v[0] = (_Float16)(a0.x * w0.x); v[1] = (_Float16)(a0.y * w0.y);
      v[2] = (_Float16)(a0.z * w0.z); v[3] = (_Float16)(a0.w * w0.w);
      v[4] = (_Float16)(a1.x * w1.x); v[5] = (_Float16)(a1.y * w1.y);
      v[6] = (_Float16)(a1.z * w1.z); v[7] = (_Float16)(a1.w * w1.w);
    }
    *(half8*)(&A_all[row * 512 + ((kg ^ (row & 7)) << 3)]) = v;
  }
  __syncthreads();

  // ---------- fwd DFT + Gaussian filter -> ABl ----------
  {
    f32x4 acc[4] = {};
    int kW[4]; bool isS[4];
#pragma unroll
    for (int ni = 0; ni < 4; ++ni) {
      int kap = wc + ni * 16 + r;             // W1 row (kappa)
      kW[ni] = kap & 127;
      isS[ni] = kap >= 128;
    }
    const int arow = min(r, 9);               // rows 9..15 -> zero row 9
    for (int u = 0; u < 16; ++u) {            // K = 512 in 16 slices of 32
      int g = u * 4 + q;
      half8 af = *(const half8*)(&A_all[arow * 512 + ((g ^ (arow & 7)) << 3)]);
      int nb = u * 32 + q * 8;
#pragma unroll
      for (int ni = 0; ni < 4; ++ni) {
        half8 bf;
#pragma unroll
        for (int jj = 0; jj < 8; ++jj) {
          int a = (kW[ni] * (nb + jj)) & 511;
          float ph = (float)a * (1.0f / 512.0f);
          bf[jj] = (_Float16)(isS[ni] ? sin_rev(ph) : cos_rev(ph));
        }
        acc[ni] = __builtin_amdgcn_mfma_f32_16x16x32_f16(af, bf, acc[ni], 0, 0, 0);
      }
    }
    // filter epilogue: ABl[row][kappa], rows 0..8 real, row 9 forced zero
    const float F0_DIFF = 780.0f / 11025.0f;
#pragma unroll
    for (int reg = 0; reg < 4; ++reg) {
      const int row = q * 4 + reg;
      if (row <= 9) {
        const int fi = max(c0 - 1 + row, 0);
        const float mu = f0_to_norm(f0[fi], f0b[fi >> 6]);
        const float sd = fminf(fmaxf(nstd[fi], 1e-12f), 1.0f) * F0_DIFF;
        const float inv_sd = 1.0f / sd;
        const float a = inv_sd * (1.0f / 256.0f);
        const float bmu = mu * inv_sd;
#pragma unroll
        for (int ni = 0; ni < 4; ++ni) {
          const int col = wc + ni * 16 + r;
          const int k = col & 127;
          float z = fmaf((float)k, a, -bmu);
          float cf = (k == 0) ? (1.0f / 512.0f) : (2.0f / 512.0f);
          float s = cf * exp2f(z * z * -0.72134752044f);  // exp(-z^2/2)
          _Float16 val = (_Float16)(acc[ni][reg] * s);
          if ((qc == 0 && row == 0) || row == 9) val = (_Float16)0.0f;
          int colg = col >> 3;
          ABl[row * 256 + ((colg ^ (row & 7)) << 3) + (col & 7)] = val;
        }
      }
    }
  }
  __syncthreads();

  // ---------- inv DFT + OLA + oscillator + mix ----------
  {
    f32x4 acc2[4] = {};
    const int a1row = min(1 + r, 9);          // AB[c0+j]   (current chunk)
    const int a2row = min(r, 9);              // AB[c0+j-1] (prev chunk)
    int nB[4];
#pragma unroll
    for (int ni = 0; ni < 4; ++ni) nB[ni] = wc + ni * 16 + r;  // sample n
    for (int u = 0; u < 8; ++u) {             // K = 256 in 8 slices of 32
      int gg = u * 4 + q;
      half8 af1 = *(const half8*)(&ABl[a1row * 256 + ((gg ^ (a1row & 7)) << 3)]);
      half8 af2 = *(const half8*)(&ABl[a2row * 256 + ((gg ^ (a2row & 7)) << 3)]);
      int kb = u * 32 + q * 8;
#pragma unroll
      for (int ni = 0; ni < 4; ++ni) {
        half8 bf1, bf2;
#pragma unroll
        for (int jj = 0; jj < 8; ++jj) {
          int kap = kb + jj;
          int k = kap & 127;
          float ph1 = (float)((k * nB[ni]) & 511) * (1.0f / 512.0f);
          float ph2 = (float)((k * (nB[ni] + 256)) & 511) * (1.0f / 512.0f);
          if (kap >= 128) {
            bf1[jj] = (_Float16)sin_rev(ph1);
            bf2[jj] = (_Float16)sin_rev(ph2);
          } else {
            bf1[jj] = (_Float16)cos_rev(ph1);
            bf2[jj] = (_Float16)cos_rev(ph2);
          }
        }
        acc2[ni] = __builtin_amdgcn_mfma_f32_16x16x32_f16(af1, bf1, acc2[ni], 0, 0, 0);
        acc2[ni] = __builtin_amdgcn_mfma_f32_16x16x32_f16(af2, bf2, acc2[ni], 0, 0, 0);
      }
    }

    // final epilogue: analytic phase + Chebyshev harmonics + mix
#pragma unroll
    for (int reg = 0; reg < 4; ++reg) {
      const int crow = q * 4 + reg;           // chunk within this block
      if (crow < 8) {
        const int c = qc * 8 + crow;          // chunk within be
#pragma unroll
        for (int ni = 0; ni < 4; ++ni) {
          const int n = wc + ni * 16 + r;
          const int t = c * 256 + n;
          float pos = ((float)t + 0.5f) * (1.0f / 256.0f) - 0.5f;
          pos = fminf(fmaxf(pos, 0.0f), 63.0f);
          int i0 = (int)pos;
          int i1 = min(i0 + 1, 63);
          float w = pos - (float)i0;

          float pph;
          if (t < 128) {
            pph = (float)(t + 1) * Fs[0];
          } else {
            int s = (t - 128) >> 8;
            float u1 = (float)((t - 128) - (s << 8) + 1);
            pph = Gs[s] + fmaf(Ds[s] * (1.0f / 512.0f), u1 * u1, u1 * Fs[s]);
          }
          pph = pph - 2.0f * floorf(pph * 0.5f);   // phase mod 2 (pi units)
          float xv = pph * 0.5f;
          float sb = sin_rev(xv);
          float cb = cos_rev(xv);
          float C = 2.0f * cb;

          float fund = sb * (oscE[i0] * (1.0f - w) + oscE[i1] * w);
          float d0 = 0.0f, d1 = 0.0f;
          float sp = sb;
          float scur = C * sb;
#pragma unroll
          for (int hq = 0; hq < 8; ++hq) {
            float4 qa = qe4[hq * 64 + i0];
            float4 qb = qe4[hq * 64 + i1];
            d0 = fmaf(scur, qa.x, d0); d1 = fmaf(scur, qb.x, d1);
            sp = fmaf(C, scur, -sp);
            d0 = fmaf(sp, qa.y, d0);   d1 = fmaf(sp, qb.y, d1);
            scur = fmaf(C, sp, -scur);
            d0 = fmaf(scur, qa.z, d0); d1 = fmaf(scur, qb.z, d1);
            sp = fmaf(C, scur, -sp);
            d0 = fmaf(sp, qa.w, d0);   d1 = fmaf(sp, qb.w, d1);
            scur = fmaf(C, sp, -scur);
          }
          float osc = fund + d0 * (1.0f - w) + d1 * w;
          float mix = oenv[i0] * (1.0f - w) + oenv[i1] * w;
          out[(size_t)be * NSAMP + t] = fmaf(osc, mix, acc2[ni][reg] * (1.0f - mix));
        }
      }
    }
  }
}

// ---------------------------------------------------------------------------
extern "C" void kernel_launch(void* const* d_in, const int* in_sizes, int n_in,
                              void* d_out, int out_size, void* d_ws, size_t ws_size,
                              hipStream_t stream) {
  const float* f0           = (const float*)d_in[0];
  const float* overall_env  = (const float*)d_in[1];
  const float* osc_env      = (const float*)d_in[2];
  // d_in[3] = noise_env: unused by the reference
  const float* harm_env     = (const float*)d_in[4];
  const float* noise_std    = (const float*)d_in[5];
  const float* f0_base      = (const float*)d_in[6];
  const float* noise_frames = (const float*)d_in[7];
  float* out = (float*)d_out;

  // single launch, no workspace, no inter-block communication
  mono_k<<<1024, 256, 0, stream>>>(
      noise_frames, f0, noise_std, f0_base, overall_env, osc_env, harm_env, out);
}

// Round 14
// 33.444 us; speedup vs baseline: 3.0970x; 2.4901x over previous
//
#include <hip/hip_runtime.h>
#include <math.h>

// ---- problem constants ----
#define SEQ 64
#define NSAMP 16384
#define NHARM 32
#define NWS 512
#define NSTEP 256
#define BE 128            // B*E = 8*16
#define NFRAMES 8192      // BE * SEQ

typedef _Float16 half8 __attribute__((ext_vector_type(8)));
typedef float f32x4 __attribute__((ext_vector_type(4)));

__device__ __forceinline__ float sin_rev(float x) {  // sin(2*pi*x)
  float r; asm("v_sin_f32 %0, %1" : "=v"(r) : "v"(x)); return r;
}
__device__ __forceinline__ float cos_rev(float x) {  // cos(2*pi*x)
  float r; asm("v_cos_f32 %0, %1" : "=v"(r) : "v"(x)); return r;
}
__device__ __forceinline__ float clip01(float v) { return fminf(fmaxf(v, 0.0f), 1.0f); }

__device__ __forceinline__ float f0_to_norm(float f0v, float bl) {
  const float NYQ = 11025.0f;
  const float MIN_F0 = 20.0f / 11025.0f;
  const float F0_DIFF = 780.0f / 11025.0f;
  float v = fminf(fmaxf(f0v, -0.5f), 0.5f);
  float erb = (0.108f * (bl * NYQ) + 24.7f) / NYQ;
  float fv = clip01(bl + v * erb);
  return MIN_F0 + fv * F0_DIFF;
}

// ---------------------------------------------------------------------------
// Kernel 1: forward GEMM (32x64 tiles, 4 blk/CU) + W2 table generation.
//   blocks [0,256):    W2[512][256] twiddles (2 rows/block; consumer is the
//                      NEXT launch -> no race).
//   blocks [256,1280): AB[8192][256] = filt( hann(frames) x W1^T ), f16 out.
//     W1 twiddles are GENERATED IN-LDS via trig (16 v_sin|v_cos per thread
//     per K-step) -- no W1 buffer, no prep launch. VALU cost hides under the
//     HBM-bound A stream. XCD swizzle: the 4 bn-blocks of one 32-frame
//     stripe share physical index mod 8 -> same XCD -> A re-reads L2-hit.
// ---------------------------------------------------------------------------
__global__ __launch_bounds__(256) void gemmf_k(const float* __restrict__ Af,
                                               _Float16* __restrict__ Cout,
                                               _Float16* __restrict__ W2,
                                               const float* __restrict__ f0,
                                               const float* __restrict__ nstd,
                                               const float* __restrict__ f0b) {
  const int tid = threadIdx.x;

  if (blockIdx.x < 256) {   // ---- W2 generation ----
    const int k = tid & 127;
    const bool isSin = tid >= 128;
#pragma unroll
    for (int rr = 0; rr < 2; ++rr) {
      const int n = blockIdx.x * 2 + rr;
      int a = (k * n) & 511;
      float ph = (float)a * (1.0f / 512.0f);
      W2[n * 256 + tid] = (_Float16)(isSin ? sin_rev(ph) : cos_rev(ph));
    }
    return;
  }

  // ---- GEMM: swizzled block decode (1024 blocks) ----
  const int p = blockIdx.x - 256;          // [0,1024)
  const int x = p & 7, j = p >> 3;         // j in [0,128)
  const int mstripe = ((j >> 2) << 3) + x; // [0,256)
  const int bn0 = (j & 3) * 64;
  const int m0 = mstripe * 32;

  const int Kt = 512;
  const int wave = tid >> 6, lane = tid & 63;
  const int r = lane & 15, q = lane >> 4;
  const int wr = (wave & 1) * 16;          // A-row (frame) sub-tile
  const int wc = (wave >> 1) * 32;         // B-row (kappa) sub-tile
  __shared__ __align__(16) _Float16 Ash[2][32 * 64];   // 8 KB
  __shared__ __align__(16) _Float16 Bsh[2][64 * 64];   // 16 KB
  __shared__ __align__(16) float whann[512];           // 2 KB

  const int nT = Kt >> 6;
  const int srowA = tid >> 3;              // 0..31 (one granule per thread)
  const int srowB0 = tid >> 3, srowB1 = (256 + tid) >> 3;
  const int skg = tid & 7;

  half8 ra, rb[2];
  f32x4 acc[2] = {};

  whann[tid] = 0.5f - 0.5f * cos_rev((float)tid * (1.0f / 512.0f));
  whann[tid + 256] = 0.5f - 0.5f * cos_rev((float)(tid + 256) * (1.0f / 512.0f));
  __syncthreads();

  // B-tile twiddle constants for this thread (uniform rows across K-steps)
  const int kB0 = (bn0 + srowB0) & 127;
  const int kB1 = (bn0 + srowB1) & 127;
  const bool sB0 = (bn0 + srowB0) >= 128;
  const bool sB1 = (bn0 + srowB1) >= 128;

  auto load_a = [&](int kk) {
    const float* s0 = Af + (size_t)(m0 + srowA) * Kt + kk + skg * 8;
    float4 a0 = ((const float4*)s0)[0], a1 = ((const float4*)s0)[1];
    float4 w0 = *(const float4*)(&whann[kk + skg * 8]);
    float4 w1 = *(const float4*)(&whann[kk + skg * 8 + 4]);
    ra[0] = (_Float16)(a0.x * w0.x); ra[1] = (_Float16)(a0.y * w0.y);
    ra[2] = (_Float16)(a0.z * w0.z); ra[3] = (_Float16)(a0.w * w0.w);
    ra[4] = (_Float16)(a1.x * w1.x); ra[5] = (_Float16)(a1.y * w1.y);
    ra[6] = (_Float16)(a1.z * w1.z); ra[7] = (_Float16)(a1.w * w1.w);
  };
  auto gen_b = [&](int kk) {  // W1 values via trig: bit-identical to table
    const int nbase = kk + skg * 8;
#pragma unroll
    for (int jj = 0; jj < 8; ++jj) {
      const int n = nbase + jj;
      float ph0 = (float)((kB0 * n) & 511) * (1.0f / 512.0f);
      float ph1 = (float)((kB1 * n) & 511) * (1.0f / 512.0f);
      rb[0][jj] = (_Float16)(sB0 ? sin_rev(ph0) : cos_rev(ph0));
      rb[1][jj] = (_Float16)(sB1 ? sin_rev(ph1) : cos_rev(ph1));
    }
  };
  auto store_lds = [&](int b) {
    *(half8*)(&Ash[b][srowA * 64 + ((skg ^ (srowA & 7)) << 3)]) = ra;
    *(half8*)(&Bsh[b][srowB0 * 64 + ((skg ^ (srowB0 & 7)) << 3)]) = rb[0];
    *(half8*)(&Bsh[b][srowB1 * 64 + ((skg ^ (srowB1 & 7)) << 3)]) = rb[1];
  };

  load_a(0);
  gen_b(0);
  store_lds(0);

  for (int t = 0;;) {
    if (t + 1 < nT) { load_a((t + 1) << 6); gen_b((t + 1) << 6); }
    __syncthreads();
    const int b = t & 1;
#pragma unroll
    for (int ks = 0; ks < 2; ++ks) {
      const int kg = ks * 4 + q;
      const int ar = wr + r;
      half8 af = *(const half8*)(&Ash[b][ar * 64 + ((kg ^ (ar & 7)) << 3)]);
#pragma unroll
      for (int ni = 0; ni < 2; ++ni) {
        const int br = wc + ni * 16 + r;
        half8 bf = *(const half8*)(&Bsh[b][br * 64 + ((kg ^ (br & 7)) << 3)]);
        acc[ni] = __builtin_amdgcn_mfma_f32_16x16x32_f16(af, bf, acc[ni], 0, 0, 0);
      }
    }
    if (t + 1 >= nT) break;
    __syncthreads();
    store_lds((t + 1) & 1);
    ++t;
  }

  const float F0_DIFF = 780.0f / 11025.0f;
#pragma unroll
  for (int reg = 0; reg < 4; ++reg) {
    const int row = m0 + wr + q * 4 + reg;   // frame
    const float mu = f0_to_norm(f0[row], f0b[row >> 6]);
    const float sd = fminf(fmaxf(nstd[row], 1e-12f), 1.0f) * F0_DIFF;
    const float inv_sd = 1.0f / sd;
    const float a = inv_sd * (1.0f / 256.0f);
    const float bmu = mu * inv_sd;
#pragma unroll
    for (int ni = 0; ni < 2; ++ni) {
      const int col = bn0 + wc + ni * 16 + r;  // kappa
      const int k = col & 127;
      float z = fmaf((float)k, a, -bmu);
      float cf = (k == 0) ? (1.0f / 512.0f) : (2.0f / 512.0f);
      float s = cf * exp2f(z * z * -0.72134752044f);  // exp(-z^2/2)
      Cout[(size_t)row * 256 + col] = (_Float16)(acc[ni][reg] * s);
    }
  }
}

// ---------------------------------------------------------------------------
// Kernel 2: fused inverse DFT + OLA + oscillator bank + mix.
// 32-chunk M-tiles, grid 1024 = be(128) x chalf(2) x n0(4), XCD-swizzled.
// T14 reg-staging: next K-step's A/W2 loads issue BEFORE the current MFMA
// (latency hides under compute), LDS write happens after the barrier.
// ---------------------------------------------------------------------------
__global__ __launch_bounds__(256) void invfin_k(const _Float16* __restrict__ AB,
                                                const _Float16* __restrict__ W2,
                                                const float* __restrict__ f0,
                                                const float* __restrict__ f0b,
                                                const float* __restrict__ oenv_g,
                                                const float* __restrict__ oscenv_g,
                                                const float* __restrict__ henv_g,
                                                float* __restrict__ out) {
  const int p = blockIdx.x;                // [0,1024)
  const int x = p & 7, j = p >> 3;         // j in [0,128)
  const int be = ((j >> 3) << 3) + x;      // [0,128)
  const int sub = j & 7;
  const int chalf = sub >> 2;              // 0/1: chunk half
  const int n0 = (sub & 3) * 64;           // sample-within-chunk base
  const int m0c = be * 64 + chalf * 32;    // global chunk base of this tile
  const int tid = threadIdx.x;
  const int wave = tid >> 6, lane = tid & 63;
  const int r = lane & 15, q = lane >> 4;
  const int wr = (wave & 1) * 16;          // chunk-row sub-tile
  const int wc = (wave >> 1) * 32;         // sample-col sub-tile

  __shared__ __align__(16) _Float16 A2sh[33 * 64];   // chunks m0c-1 .. m0c+31
  __shared__ __align__(16) _Float16 B1sh[64 * 64];   // W2[n0+row]
  __shared__ __align__(16) _Float16 B2sh[64 * 64];   // W2[n0+row+256]
  __shared__ __align__(16) float4 qe4[8 * SEQ];
  __shared__ float oenv[SEQ], oscE[SEQ];
  __shared__ float Fs[SEQ], Ds[SEQ], Gs[SEQ];

  if (tid < SEQ) {
    oenv[tid] = clip01(oenv_g[be * SEQ + tid]);
    oscE[tid] = clip01(oscenv_g[be * SEQ + tid]);
    Fs[tid] = f0_to_norm(f0[be * SEQ + tid], f0b[be]);
  }
  __syncthreads();

  // wave 0: segment phase-prefix scan (f64, 6 shuffle steps), mod 2
  if (tid < SEQ) {
    const int s = tid;
    float fcur = Fs[s];
    float fnxt = (s < 63) ? Fs[s + 1] : Fs[63];
    Ds[s] = fnxt - fcur;                               // D[63] = 0
    double term = 128.0 * ((double)fcur + (double)fnxt);
    double sc = term;
#pragma unroll
    for (int off = 1; off < 64; off <<= 1) {
      double u = __shfl_up(sc, off, 64);
      if (s >= off) sc += u;
    }
    double C = 128.0 * (double)Fs[0] + (sc - term);    // exclusive prefix
    Gs[s] = (float)(C - 2.0 * floor(C * 0.5));
  }

  // stage qe4 (osc_env * harm_env)
  for (int idx = tid; idx < 8 * SEQ; idx += 256) {
    int hq = idx >> 6, s = idx & 63;
    const float* hb = henv_g + (size_t)be * (NHARM * SEQ) + (4 * hq) * SEQ + s;
    float e = oscE[s];
    qe4[idx] = make_float4(e * clip01(hb[0]), e * clip01(hb[64]),
                           e * clip01(hb[128]), e * clip01(hb[192]));
  }

  // T14 staging state: A granule 0 (all threads) + A granule 1 (tid<8) + 4 B
  half8 raA0, raA1, rbB[4];
  const int rowA0 = tid >> 3, kgA0 = tid & 7;           // g = tid
  const int rowA1 = (256 + tid) >> 3;                   // g = 256+tid (tid<8)

  auto stage_load = [&](int kk) {
    {
      half8 v = {0, 0, 0, 0, 0, 0, 0, 0};
      if (rowA0 > 0 || chalf == 1)
        v = *(const half8*)(AB + (size_t)(m0c - 1 + rowA0) * 256 + kk + kgA0 * 8);
      raA0 = v;
    }
    if (tid < 8)
      raA1 = *(const half8*)(AB + (size_t)(m0c - 1 + rowA1) * 256 + kk + kgA0 * 8);
#pragma unroll
    for (int it = 0; it < 4; ++it) {
      int g = it * 256 + tid;
      int row = (g >> 3) & 63;
      bool second = g >= 512;
      int wrow = n0 + row + (second ? 256 : 0);
      rbB[it] = *(const half8*)(W2 + (size_t)wrow * 256 + kk + (g & 7) * 8);
    }
  };
  auto stage_write = [&]() {
    *(half8*)(&A2sh[rowA0 * 64 + ((kgA0 ^ (rowA0 & 7)) << 3)]) = raA0;
    if (tid < 8)
      *(half8*)(&A2sh[rowA1 * 64 + ((kgA0 ^ (rowA1 & 7)) << 3)]) = raA1;
#pragma unroll
    for (int it = 0; it < 4; ++it) {
      int g = it * 256 + tid;
      int row = (g >> 3) & 63;
      _Float16* dst = (g >= 512) ? B2sh : B1sh;
      *(half8*)(&dst[row * 64 + (((g & 7) ^ (row & 7)) << 3)]) = rbB[it];
    }
  };

  f32x4 acc[2] = {};
  stage_load(0);
  stage_write();
  __syncthreads();

  for (int t = 0;;) {
    if (t < 3) stage_load((t + 1) << 6);   // issue loads; latency hides in MFMA
#pragma unroll
    for (int ks = 0; ks < 2; ++ks) {
      const int kg = ks * 4 + q;
      const int ra1 = 1 + wr + r;
      const int ra2 = wr + r;
      half8 af1 = *(const half8*)(&A2sh[ra1 * 64 + ((kg ^ (ra1 & 7)) << 3)]);
      half8 af2 = *(const half8*)(&A2sh[ra2 * 64 + ((kg ^ (ra2 & 7)) << 3)]);
#pragma unroll
      for (int ni = 0; ni < 2; ++ni) {
        const int rb = wc + ni * 16 + r;
        const int sw = (kg ^ (rb & 7)) << 3;
        half8 bf1 = *(const half8*)(&B1sh[rb * 64 + sw]);
        half8 bf2 = *(const half8*)(&B2sh[rb * 64 + sw]);
        acc[ni] = __builtin_amdgcn_mfma_f32_16x16x32_f16(af1, bf1, acc[ni], 0, 0, 0);
        acc[ni] = __builtin_amdgcn_mfma_f32_16x16x32_f16(af2, bf2, acc[ni], 0, 0, 0);
      }
    }
    if (t == 3) break;
    __syncthreads();
    stage_write();
    __syncthreads();
    ++t;
  }

  // epilogue: analytic phase + oscillator bank + mix, in-register
#pragma unroll
  for (int reg = 0; reg < 4; ++reg) {
    const int c = chalf * 32 + wr + q * 4 + reg;     // chunk within be
#pragma unroll
    for (int ni = 0; ni < 2; ++ni) {
      const int n = n0 + wc + ni * 16 + r;
      const int t = c * 256 + n;
      float pos = ((float)t + 0.5f) * (1.0f / 256.0f) - 0.5f;
      pos = fminf(fmaxf(pos, 0.0f), 63.0f);
      int i0 = (int)pos;
      int i1 = min(i0 + 1, 63);
      float w = pos - (float)i0;

      float pph;
      if (t < 128) {
        pph = (float)(t + 1) * Fs[0];
      } else {
        int s = (t - 128) >> 8;
        float u1 = (float)((t - 128) - (s << 8) + 1);
        pph = Gs[s] + fmaf(Ds[s] * (1.0f / 512.0f), u1 * u1, u1 * Fs[s]);
      }
      pph = pph - 2.0f * floorf(pph * 0.5f);         // phase mod 2 (pi units)
      float xv = pph * 0.5f;
      float sb = sin_rev(xv);
      float cb = cos_rev(xv);
      float C = 2.0f * cb;

      float fund = sb * (oscE[i0] * (1.0f - w) + oscE[i1] * w);
      float d0 = 0.0f, d1 = 0.0f;
      float sp = sb;
      float scur = C * sb;
#pragma unroll
      for (int hq = 0; hq < 8; ++hq) {
        float4 qa = qe4[hq * 64 + i0];
        float4 qb = qe4[hq * 64 + i1];
        d0 = fmaf(scur, qa.x, d0); d1 = fmaf(scur, qb.x, d1);
        sp = fmaf(C, scur, -sp);
        d0 = fmaf(sp, qa.y, d0);   d1 = fmaf(sp, qb.y, d1);
        scur = fmaf(C, sp, -scur);
        d0 = fmaf(scur, qa.z, d0); d1 = fmaf(scur, qb.z, d1);
        sp = fmaf(C, scur, -sp);
        d0 = fmaf(sp, qa.w, d0);   d1 = fmaf(sp, qb.w, d1);
        scur = fmaf(C, sp, -scur);
      }
      float osc = fund + d0 * (1.0f - w) + d1 * w;
      float mix = oenv[i0] * (1.0f - w) + oenv[i1] * w;
      out[(size_t)be * NSAMP + t] = fmaf(osc, mix, acc[ni][reg] * (1.0f - mix));
    }
  }
}

// ---------------------------------------------------------------------------
extern "C" void kernel_launch(void* const* d_in, const int* in_sizes, int n_in,
                              void* d_out, int out_size, void* d_ws, size_t ws_size,
                              hipStream_t stream) {
  const float* f0           = (const float*)d_in[0];
  const float* overall_env  = (const float*)d_in[1];
  const float* osc_env      = (const float*)d_in[2];
  // d_in[3] = noise_env: unused by the reference
  const float* harm_env     = (const float*)d_in[4];
  const float* noise_std    = (const float*)d_in[5];
  const float* f0_base      = (const float*)d_in[6];
  const float* noise_frames = (const float*)d_in[7];
  float* out = (float*)d_out;

  // workspace layout
  _Float16* W2 = (_Float16*)d_ws;                         // 131,072 f16
  _Float16* AB = W2 + 512 * 256;                          // 2,097,152 f16

  // fwd: AB = filt( hann(frames) x W1^T ), W1 generated in-LDS;
  //      blocks 0..255 also write the W2 table for the next launch
  gemmf_k<<<1280, 256, 0, stream>>>(noise_frames, AB, W2, f0, noise_std, f0_base);
  // inv + OLA + oscillator bank + final mix, writes out directly
  invfin_k<<<1024, 256, 0, stream>>>(
      AB, W2, f0, f0_base, overall_env, osc_env, harm_env, out);
}